// Round 11
// baseline (109.843 us; speedup 1.0000x reference)
//
#include <hip/hip_runtime.h>

// Problem constants
#define S_   16384
#define T_   16384
#define B_   32
#define NEDGES (S_ * 64)       // 1,048,576
#define GP_  512               // producer blocks, 2048 edges each
#define EPG  2048              // edges per producer block
#define NBKT 512               // buckets of 32 targets
#define TPB  32                // targets per bucket
#define CAP_SRT 2432           // lambda=2048, +8.5 sigma

// weight = clip(att,0,1) * 0.9^delay, delay in [0,6). Exact bit-product.
__device__ __forceinline__ float edge_weight(float a, int d) {
  float w = fminf(fmaxf(a, 0.0f), 1.0f);
  float r = (d & 1) ? 0.9f : 1.0f;
  r = (d & 2) ? r * 0.81f   : r;
  r = (d & 4) ? r * 0.6561f : r;
  return w * r;
}

// ---------------------------------------------------------------------------
// K1: ONE LDS atomic per edge (packed-u8 hist, return = rank in (block,tgt)).
// Bucket-relative u8 starts rewritten IN PLACE into the swizzled histogram
// (no tofs array, no bank conflicts). Slices emerge target-sorted.
// rec[g][i]: {meta = rank<<19 | tl<<14 | src, w_bits}; ofse[g][bkt]=end<<16|st.
// cntp swizzle: word w (=t>>2, 0..4095) lives at cntp[(w&7)*512 + (w>>3)].
__global__ __launch_bounds__(512) void produce(
    const float* __restrict__ spikes,
    const float* __restrict__ att,
    const int*   __restrict__ tgt,
    const int*   __restrict__ del,
    float*    __restrict__ spikesT,
    int2*     __restrict__ rec,
    unsigned* __restrict__ ofse) {
  __shared__ float tile[32][33];             // 4.2 KB
  __shared__ int4  sbuf4[EPG / 2];           // 16 KB (2048 int2 records)
  __shared__ unsigned cntp[4096];            // 16 KB packed u8 (counts -> starts)
  __shared__ int  sofs5[NBKT];               // 2 KB bucket starts
  __shared__ int  wtot[8];
  int2* buf = (int2*)sbuf4;

  const int g = blockIdx.x, tid = threadIdx.x;
#pragma unroll
  for (int i = 0; i < 8; ++i) cntp[i * 512 + tid] = 0u;   // coalesced

  // transpose sources [g*32, g*32+32)
  const int s0 = g * 32;
  {
    const int x = tid & 31, y = tid >> 5;
    tile[x][y]      = spikes[(size_t)y        * S_ + s0 + x];
    tile[x][y + 16] = spikes[(size_t)(y + 16) * S_ + s0 + x];
  }

  const int e4 = g * 512 + tid;
  int4   t = reinterpret_cast<const int4*>(tgt)[e4];
  float4 a = reinterpret_cast<const float4*>(att)[e4];
  int4   d = reinterpret_cast<const int4*>(del)[e4];
  const int src = e4 >> 4;                   // 4 consecutive edges: 1 source

  __syncthreads();                           // cntp + tile visible

  {
    const int b = tid & 31, j = tid >> 5;
    spikesT[(size_t)(s0 + j)      * 32 + b] = tile[j][b];
    spikesT[(size_t)(s0 + j + 16) * 32 + b] = tile[j + 16][b];
  }

  // hist + rank: ONE atomic lane-op per edge
#define SW(w) ((((w) & 7) << 9) | ((w) >> 3))
  int r0, r1, r2, r3;
  {
    unsigned o;
    o = __hip_atomic_fetch_add(&cntp[SW(t.x >> 2)], 1u << (8 * (t.x & 3)),
                               __ATOMIC_RELAXED, __HIP_MEMORY_SCOPE_WORKGROUP);
    r0 = (int)((o >> (8 * (t.x & 3))) & 0xFF);
    o = __hip_atomic_fetch_add(&cntp[SW(t.y >> 2)], 1u << (8 * (t.y & 3)),
                               __ATOMIC_RELAXED, __HIP_MEMORY_SCOPE_WORKGROUP);
    r1 = (int)((o >> (8 * (t.y & 3))) & 0xFF);
    o = __hip_atomic_fetch_add(&cntp[SW(t.z >> 2)], 1u << (8 * (t.z & 3)),
                               __ATOMIC_RELAXED, __HIP_MEMORY_SCOPE_WORKGROUP);
    r2 = (int)((o >> (8 * (t.z & 3))) & 0xFF);
    o = __hip_atomic_fetch_add(&cntp[SW(t.w >> 2)], 1u << (8 * (t.w & 3)),
                               __ATOMIC_RELAXED, __HIP_MEMORY_SCOPE_WORKGROUP);
    r3 = (int)((o >> (8 * (t.w & 3))) & 0xFF);
  }
  __syncthreads();

  // thread tid = bucket tid (words w = tid*8+i -> swizzled addr i*512+tid):
  // compute bucket total + rewrite counts as bucket-relative u8 starts IN PLACE
  unsigned wreg[8];
  int tot = 0;
#pragma unroll
  for (int i = 0; i < 8; ++i) {
    const unsigned c = cntp[i * 512 + tid];
    wreg[i] = c;
    tot += (c & 0xFF) + ((c >> 8) & 0xFF) + ((c >> 16) & 0xFF) + (c >> 24);
  }
  {
    int run = 0;
#pragma unroll
    for (int i = 0; i < 8; ++i) {
      unsigned rel = 0;
#pragma unroll
      for (int bb = 0; bb < 4; ++bb) {
        rel |= (unsigned)run << (8 * bb);
        run += (wreg[i] >> (8 * bb)) & 0xFF;
      }
      cntp[i * 512 + tid] = rel;             // coalesced rewrite
    }
  }
  // scan bucket totals (512) -> bucket starts
  int incl = tot;
#pragma unroll
  for (int off = 1; off < 64; off <<= 1) {
    int u = __shfl_up(incl, off);
    if ((tid & 63) >= off) incl += u;
  }
  if ((tid & 63) == 63) wtot[tid >> 6] = incl;
  __syncthreads();
  {
    int base = 0;
    for (int i = 0; i < (tid >> 6); ++i) base += wtot[i];
    const int start = base + incl - tot;
    sofs5[tid] = start;
    ofse[(size_t)g * NBKT + tid] =
        ((unsigned)(start + tot) << 16) | (unsigned)start;
  }
  __syncthreads();                           // rel-starts + sofs5 ready

  // place: position = sofs5[bucket] + rel[t] + rank  (unique, no atomics)
#define PUT(TT, RK, AV, DV)                                                   \
  {                                                                           \
    const unsigned relw = cntp[SW((TT) >> 2)];                                \
    const int p = sofs5[(TT) >> 5] +                                          \
                  (int)((relw >> (8 * ((TT) & 3))) & 0xFF) + (RK);            \
    buf[p] = make_int2((((RK) & 31) << 19) | (((TT) & 31) << 14) | src,       \
                       __float_as_int(edge_weight((AV), (DV))));              \
  }
  PUT(t.x, r0, a.x, d.x)
  PUT(t.y, r1, a.y, d.y)
  PUT(t.z, r2, a.z, d.z)
  PUT(t.w, r3, a.w, d.w)
#undef PUT
#undef SW
  __syncthreads();

  int4* recO = reinterpret_cast<int4*>(rec) + (size_t)g * (EPG / 2);
  recO[tid]       = sbuf4[tid];
  recO[tid + 512] = sbuf4[tid + 512];
}

// ---------------------------------------------------------------------------
// K2: ZERO atomics. Slices are target-sorted with ranks; run boundaries give
// per-(g,tl) counts non-atomically -> 2D prefix -> exact srt slots -> gather.
__global__ __launch_bounds__(512) void consume(
    const int2*     __restrict__ rec,
    const unsigned* __restrict__ ofse,
    const float*    __restrict__ spikesT,
    float* __restrict__ out) {
  __shared__ int2  srt[CAP_SRT];                 // 19.0 KB
  __shared__ unsigned short mat[TPB][GP_ + 2];   // 32.1 KB counts -> lpos
  __shared__ float otile[TPB][33];               // 4.2 KB
  __shared__ unsigned sse[GP_];                  // 2 KB
  __shared__ int prt[16][TPB + 1];               // 2.1 KB
  __shared__ int ttot[TPB];
  __shared__ int ofs[TPB + 1];

  const int k = blockIdx.x, tid = threadIdx.x;
  const int b = tid & 31, hw = tid >> 5;         // hw 0..15
  const int sub = b >> 3, j0 = b & 7;            // 8-lane subgroup

  // zero count matrix (u32 view) + load slice directory
  {
    unsigned* m32 = (unsigned*)mat;
    for (int i = tid; i < TPB * (GP_ + 2) / 2; i += 512) m32[i] = 0u;
  }
  sse[tid] = ofse[(size_t)tid * NBKT + k];
  __syncthreads();

  // pass A: read records (contiguous 8-chunks), detect run boundaries,
  // write per-(g,tl) counts; keep records in registers.
  int2 rr[16];
  int  nrec = 0;
#pragma unroll
  for (int it = 0; it < 8; ++it) {
    const int g = it * 64 + hw * 4 + sub;
    const unsigned u = sse[g];
    const int st = (int)(u & 0xFFFF);
    const int n  = (int)(u >> 16) - st;
    const int2* slice = rec + (size_t)g * EPG + st;
    for (int c0 = 0; c0 < n; c0 += 8) {
      const int j = c0 + j0;
      int2 r = make_int2(0, 0);
      if (j < n) r = slice[j];
      const int nx = __shfl_down(r.x, 1);        // lane j+1's record (same chunk)
      if (j < n && nrec < 16) {
        const int tl = (r.x >> 14) & 31;
        bool last;
        if (j + 1 >= n) last = true;
        else if (j0 < 7) last = ((nx >> 14) & 31) != tl;
        else             last = ((slice[j + 1].x >> 14) & 31) != tl;
        if (last) mat[tl][g] = (unsigned short)(((r.x >> 19) & 31) + 1);
        rr[nrec++] = r;
      }
    }
  }
  __syncthreads();

  // pass B: per-target prefix over g (in place: counts -> lpos), totals
  {
    int s = 0;
    for (int j = 0; j < 32; ++j) s += mat[b][hw * 32 + j];
    prt[hw][b] = s;
  }
  __syncthreads();
  {
    int pbase = 0;
    for (int c = 0; c < hw; ++c) pbase += prt[c][b];
    int run = pbase;
    for (int j = 0; j < 32; ++j) {
      const int c = mat[b][hw * 32 + j];
      mat[b][hw * 32 + j] = (unsigned short)run;
      run += c;
    }
    if (hw == 15) ttot[b] = run;
  }
  __syncthreads();
  if (tid < 32) {
    int v = ttot[tid], ii = v;
#pragma unroll
    for (int off = 1; off < 32; off <<= 1) {
      int u = __shfl_up(ii, off);
      if (tid >= off) ii += u;
    }
    ofs[tid] = ii - v;
    if (tid == 31) ofs[32] = ii;
  }
  __syncthreads();

  // pass C: replay traversal, exact slots, plain ds_write
  {
    int c = 0;
#pragma unroll
    for (int it = 0; it < 8; ++it) {
      const int g = it * 64 + hw * 4 + sub;
      const unsigned u = sse[g];
      const int st = (int)(u & 0xFFFF);
      const int n  = (int)(u >> 16) - st;
      for (int c0 = 0; c0 < n; c0 += 8) {
        const int j = c0 + j0;
        if (j < n && c < 16) {
          int2 r = rr[c++];
          const int tl  = (r.x >> 14) & 31;
          const int rk  = (r.x >> 19) & 31;
          const int idx = ofs[tl] + (int)mat[tl][g] + rk;
          if (idx < CAP_SRT) srt[idx] = r;
        }
      }
    }
  }
  __syncthreads();

  // gather: half-wave hw owns targets hw (acc0), hw+16 (acc1); lane = batch
  float acc0 = 0.f, acc1 = 0.f;
  {
    int e        = min(ofs[hw], CAP_SRT);
    const int e1 = min(ofs[hw + 1], CAP_SRT);
    for (; e + 4 <= e1; e += 4) {
      int2 q0 = srt[e], q1 = srt[e + 1], q2 = srt[e + 2], q3 = srt[e + 3];
      float f0 = spikesT[(size_t)(q0.x & 0x3FFF) * 32 + b];
      float f1 = spikesT[(size_t)(q1.x & 0x3FFF) * 32 + b];
      float f2 = spikesT[(size_t)(q2.x & 0x3FFF) * 32 + b];
      float f3 = spikesT[(size_t)(q3.x & 0x3FFF) * 32 + b];
      acc0 = fmaf(__int_as_float(q0.y), f0, acc0);
      acc0 = fmaf(__int_as_float(q1.y), f1, acc0);
      acc0 = fmaf(__int_as_float(q2.y), f2, acc0);
      acc0 = fmaf(__int_as_float(q3.y), f3, acc0);
    }
    for (; e < e1; ++e) {
      int2 q = srt[e];
      acc0 = fmaf(__int_as_float(q.y), spikesT[(size_t)(q.x & 0x3FFF) * 32 + b], acc0);
    }
  }
  {
    int e        = min(ofs[hw + 16], CAP_SRT);
    const int e1 = min(ofs[hw + 17], CAP_SRT);
    for (; e + 4 <= e1; e += 4) {
      int2 q0 = srt[e], q1 = srt[e + 1], q2 = srt[e + 2], q3 = srt[e + 3];
      float f0 = spikesT[(size_t)(q0.x & 0x3FFF) * 32 + b];
      float f1 = spikesT[(size_t)(q1.x & 0x3FFF) * 32 + b];
      float f2 = spikesT[(size_t)(q2.x & 0x3FFF) * 32 + b];
      float f3 = spikesT[(size_t)(q3.x & 0x3FFF) * 32 + b];
      acc1 = fmaf(__int_as_float(q0.y), f0, acc1);
      acc1 = fmaf(__int_as_float(q1.y), f1, acc1);
      acc1 = fmaf(__int_as_float(q2.y), f2, acc1);
      acc1 = fmaf(__int_as_float(q3.y), f3, acc1);
    }
    for (; e < e1; ++e) {
      int2 q = srt[e];
      acc1 = fmaf(__int_as_float(q.y), spikesT[(size_t)(q.x & 0x3FFF) * 32 + b], acc1);
    }
  }

  // transpose 32x32 tile and write out coalesced
  otile[hw][b]      = acc0;
  otile[hw + 16][b] = acc1;
  __syncthreads();
  const int bb = tid >> 4;
  const int cc = (tid & 15) * 2;
  float2 o2 = make_float2(otile[cc][bb], otile[cc + 1][bb]);
  *reinterpret_cast<float2*>(&out[(size_t)bb * T_ + k * 32 + cc]) = o2;
}

// ---------------------------------------------------------------------------
__global__ void zero_floats(float* __restrict__ p, int n) {
  int i = blockIdx.x * blockDim.x + threadIdx.x;
  if (i < n) p[i] = 0.0f;
}

// Emergency fallback (tiny ws): direct global atomics, weights inline.
__global__ void naive_kernel(const float* __restrict__ spikes,
                             const float* __restrict__ att,
                             const int*   __restrict__ tgt,
                             const int*   __restrict__ del,
                             float*       __restrict__ out) {
  int i = blockIdx.x * blockDim.x + threadIdx.x;
  if (i >= NEDGES) return;
  int   s = i >> 6;
  int   t = tgt[i];
  float w = edge_weight(att[i], del[i]);
  for (int b = 0; b < B_; ++b)
    unsafeAtomicAdd(&out[(size_t)b * T_ + t], w * spikes[(size_t)b * S_ + s]);
}

// ---------------------------------------------------------------------------
extern "C" void kernel_launch(void* const* d_in, const int* in_sizes, int n_in,
                              void* d_out, int out_size, void* d_ws, size_t ws_size,
                              hipStream_t stream) {
  const float* spikes = (const float*)d_in[0];
  const float* att    = (const float*)d_in[1];
  const int*   tgt    = (const int*)d_in[2];
  const int*   del    = (const int*)d_in[3];
  float*       out    = (float*)d_out;

  const size_t spikesT_bytes = (size_t)S_ * B_ * sizeof(float);           // 2 MB
  const size_t rec_bytes     = (size_t)NEDGES * sizeof(int2);             // 8 MB
  const size_t ofse_bytes    = (size_t)GP_ * NBKT * sizeof(unsigned);     // 1 MB
  const size_t need = spikesT_bytes + rec_bytes + ofse_bytes + 64;

  if (ws_size < need) {
    zero_floats<<<(B_ * T_ + 255) / 256, 256, 0, stream>>>(out, B_ * T_);
    naive_kernel<<<(NEDGES + 255) / 256, 256, 0, stream>>>(spikes, att, tgt, del, out);
    return;
  }

  char* p = (char*)d_ws;
  float*    spikesT = (float*)p;    p += spikesT_bytes;
  int2*     rec     = (int2*)p;     p += rec_bytes;
  unsigned* ofse    = (unsigned*)p;

  produce<<<GP_, 512, 0, stream>>>(spikes, att, tgt, del, spikesT, rec, ofse);
  consume<<<NBKT, 512, 0, stream>>>(rec, ofse, spikesT, out);
}

// Round 12
// 100.372 us; speedup vs baseline: 1.0944x; 1.0944x over previous
//
#include <hip/hip_runtime.h>

// Problem constants
#define S_   16384
#define T_   16384
#define B_   32
#define NEDGES (S_ * 64)       // 1,048,576
#define GP_  512               // producer blocks, 2048 edges each
#define EPG  2048              // edges per producer block
#define NBKT 512               // buckets of 32 targets
#define TPB  32                // targets per bucket
#define CAP_SRT 2432           // lambda=2048, +8.5 sigma
#define LPW  514               // lpos row stride (u16), pad 2 breaks bank alias

// weight = clip(att,0,1) * 0.9^delay, delay in [0,6). Exact bit-product.
__device__ __forceinline__ float edge_weight(float a, int d) {
  float w = fminf(fmaxf(a, 0.0f), 1.0f);
  float r = (d & 1) ? 0.9f : 1.0f;
  r = (d & 2) ? r * 0.81f   : r;
  r = (d & 4) ? r * 0.6561f : r;
  return w * r;
}

// ---------------------------------------------------------------------------
// K1 (R11 produce + count export). ONE LDS atomic per edge; packed-u8 hist,
// return value = rank within (block, target). Slices flush target-sorted.
// rec[g][i]: {meta = rank<<19 | tl<<14 | src, w_bits}
// ofse[g][bkt] = end<<16 | start
// cntm[g][bkt][8] u32: packed u8 counts (word i covers targets bkt*32+4i..+3)
__global__ __launch_bounds__(512) void produce(
    const float* __restrict__ spikes,
    const float* __restrict__ att,
    const int*   __restrict__ tgt,
    const int*   __restrict__ del,
    float*    __restrict__ spikesT,
    int2*     __restrict__ rec,
    unsigned* __restrict__ ofse,
    unsigned* __restrict__ cntm) {
  __shared__ float tile[32][33];             // 4.2 KB
  __shared__ int4  sbuf4[EPG / 2];           // 16 KB (2048 int2 records)
  __shared__ unsigned cntp[4096];            // 16 KB packed u8 (counts -> starts)
  __shared__ int  sofs5[NBKT];               // 2 KB bucket starts
  __shared__ int  wtot[8];
  int2* buf = (int2*)sbuf4;

  const int g = blockIdx.x, tid = threadIdx.x;
#pragma unroll
  for (int i = 0; i < 8; ++i) cntp[i * 512 + tid] = 0u;   // coalesced

  // transpose sources [g*32, g*32+32)
  const int s0 = g * 32;
  {
    const int x = tid & 31, y = tid >> 5;
    tile[x][y]      = spikes[(size_t)y        * S_ + s0 + x];
    tile[x][y + 16] = spikes[(size_t)(y + 16) * S_ + s0 + x];
  }

  const int e4 = g * 512 + tid;
  int4   t = reinterpret_cast<const int4*>(tgt)[e4];
  float4 a = reinterpret_cast<const float4*>(att)[e4];
  int4   d = reinterpret_cast<const int4*>(del)[e4];
  const int src = e4 >> 4;                   // 4 consecutive edges: 1 source

  __syncthreads();                           // cntp + tile visible

  {
    const int b = tid & 31, j = tid >> 5;
    spikesT[(size_t)(s0 + j)      * 32 + b] = tile[j][b];
    spikesT[(size_t)(s0 + j + 16) * 32 + b] = tile[j + 16][b];
  }

  // hist + rank: ONE atomic lane-op per edge
#define SW(w) ((((w) & 7) << 9) | ((w) >> 3))
  int r0, r1, r2, r3;
  {
    unsigned o;
    o = __hip_atomic_fetch_add(&cntp[SW(t.x >> 2)], 1u << (8 * (t.x & 3)),
                               __ATOMIC_RELAXED, __HIP_MEMORY_SCOPE_WORKGROUP);
    r0 = (int)((o >> (8 * (t.x & 3))) & 0xFF);
    o = __hip_atomic_fetch_add(&cntp[SW(t.y >> 2)], 1u << (8 * (t.y & 3)),
                               __ATOMIC_RELAXED, __HIP_MEMORY_SCOPE_WORKGROUP);
    r1 = (int)((o >> (8 * (t.y & 3))) & 0xFF);
    o = __hip_atomic_fetch_add(&cntp[SW(t.z >> 2)], 1u << (8 * (t.z & 3)),
                               __ATOMIC_RELAXED, __HIP_MEMORY_SCOPE_WORKGROUP);
    r2 = (int)((o >> (8 * (t.z & 3))) & 0xFF);
    o = __hip_atomic_fetch_add(&cntp[SW(t.w >> 2)], 1u << (8 * (t.w & 3)),
                               __ATOMIC_RELAXED, __HIP_MEMORY_SCOPE_WORKGROUP);
    r3 = (int)((o >> (8 * (t.w & 3))) & 0xFF);
  }
  __syncthreads();

  // thread tid = bucket tid; read its 8 packed count words (swizzled)
  unsigned wreg[8];
  int tot = 0;
#pragma unroll
  for (int i = 0; i < 8; ++i) {
    const unsigned c = cntp[i * 512 + tid];
    wreg[i] = c;
    tot += (c & 0xFF) + ((c >> 8) & 0xFF) + ((c >> 16) & 0xFF) + (c >> 24);
  }
  // EXPORT raw counts (coalesced 32 B/thread, 16 KB/block)
  {
    uint4* co = reinterpret_cast<uint4*>(cntm) + (((size_t)g * 512 + tid) * 2);
    co[0] = make_uint4(wreg[0], wreg[1], wreg[2], wreg[3]);
    co[1] = make_uint4(wreg[4], wreg[5], wreg[6], wreg[7]);
  }
  // rewrite counts as bucket-relative u8 starts IN PLACE
  {
    int run = 0;
#pragma unroll
    for (int i = 0; i < 8; ++i) {
      unsigned rel = 0;
#pragma unroll
      for (int bb = 0; bb < 4; ++bb) {
        rel |= (unsigned)run << (8 * bb);
        run += (wreg[i] >> (8 * bb)) & 0xFF;
      }
      cntp[i * 512 + tid] = rel;             // coalesced rewrite
    }
  }
  // scan bucket totals (512) -> bucket starts
  int incl = tot;
#pragma unroll
  for (int off = 1; off < 64; off <<= 1) {
    int u = __shfl_up(incl, off);
    if ((tid & 63) >= off) incl += u;
  }
  if ((tid & 63) == 63) wtot[tid >> 6] = incl;
  __syncthreads();
  {
    int base = 0;
    for (int i = 0; i < (tid >> 6); ++i) base += wtot[i];
    const int start = base + incl - tot;
    sofs5[tid] = start;
    ofse[(size_t)g * NBKT + tid] =
        ((unsigned)(start + tot) << 16) | (unsigned)start;
  }
  __syncthreads();                           // rel-starts + sofs5 ready

  // place: position = sofs5[bucket] + rel[t] + rank  (unique, no atomics)
#define PUT(TT, RK, AV, DV)                                                   \
  {                                                                           \
    const unsigned relw = cntp[SW((TT) >> 2)];                                \
    const int p = sofs5[(TT) >> 5] +                                          \
                  (int)((relw >> (8 * ((TT) & 3))) & 0xFF) + (RK);            \
    buf[p] = make_int2((((RK) & 31) << 19) | (((TT) & 31) << 14) | src,       \
                       __float_as_int(edge_weight((AV), (DV))));              \
  }
  PUT(t.x, r0, a.x, d.x)
  PUT(t.y, r1, a.y, d.y)
  PUT(t.z, r2, a.z, d.z)
  PUT(t.w, r3, a.w, d.w)
#undef PUT
#undef SW
  __syncthreads();

  int4* recO = reinterpret_cast<int4*>(rec) + (size_t)g * (EPG / 2);
  recO[tid]       = sbuf4[tid];
  recO[tid + 512] = sbuf4[tid + 512];
}

// ---------------------------------------------------------------------------
// K2: ZERO atomics, single traversal. Counts come pre-made from cntm; 2-level
// prefix gives absolute slot lpos[tl][g]; slot = lpos + rank; ds_write; gather.
__global__ __launch_bounds__(512) void consume(
    const int2*     __restrict__ rec,
    const unsigned* __restrict__ ofse,
    const unsigned* __restrict__ cntm,
    const float*    __restrict__ spikesT,
    float* __restrict__ out) {
  __shared__ int2  srt[CAP_SRT];               // 19.0 KB
  __shared__ unsigned cmat[512 * 9];           // 18.0 KB (pad 9)
  __shared__ unsigned short lpos[TPB * LPW];   // 32.1 KB absolute starts
  __shared__ float otile[TPB][33];             // 4.2 KB
  __shared__ unsigned sse[GP_];                // 2 KB
  __shared__ int prt[16][TPB + 1];             // 2.1 KB
  __shared__ int ttot[TPB];
  __shared__ int ofs[TPB + 1];

  const int k = blockIdx.x, tid = threadIdx.x;
  const int b = tid & 31, hw = tid >> 5;       // hw 0..15
  const int sub = b >> 3, j0 = b & 7;          // 8-lane subgroup

  sse[tid] = ofse[(size_t)tid * NBKT + k];     // parallel strided (proven OK)
  {
    const uint4* cp = reinterpret_cast<const uint4*>(cntm) +
                      (((size_t)tid * 512 + k) * 2);
    uint4 c0 = cp[0], c1 = cp[1];
    cmat[tid * 9 + 0] = c0.x; cmat[tid * 9 + 1] = c0.y;
    cmat[tid * 9 + 2] = c0.z; cmat[tid * 9 + 3] = c0.w;
    cmat[tid * 9 + 4] = c1.x; cmat[tid * 9 + 5] = c1.y;
    cmat[tid * 9 + 6] = c1.z; cmat[tid * 9 + 7] = c1.w;
  }
  __syncthreads();

  // per-chunk sums: thread (tl=b, chunk=hw) sums its 32 g's
  const int wd = b >> 2, sh = 8 * (b & 3);
  {
    int s = 0;
    for (int j = 0; j < 32; ++j) s += (cmat[(hw * 32 + j) * 9 + wd] >> sh) & 0xFF;
    prt[hw][b] = s;
  }
  __syncthreads();
  if (hw == 0) {                               // per-target totals
    int tt = 0;
    for (int c = 0; c < 16; ++c) tt += prt[c][b];
    ttot[b] = tt;
  }
  __syncthreads();
  if (tid < 32) {                              // exclusive scan of 32 totals
    int v = ttot[tid], ii = v;
#pragma unroll
    for (int off = 1; off < 32; off <<= 1) {
      int u = __shfl_up(ii, off);
      if (tid >= off) ii += u;
    }
    ofs[tid] = ii - v;
    if (tid == 31) ofs[32] = ii;
  }
  __syncthreads();
  // absolute starts lpos[tl][g] = ofs[tl] + prefix over g
  {
    int run = ofs[b];
    for (int c = 0; c < hw; ++c) run += prt[c][b];
    for (int j = 0; j < 32; ++j) {
      const int g = hw * 32 + j;
      const int c = (cmat[g * 9 + wd] >> sh) & 0xFF;
      lpos[b * LPW + g] = (unsigned short)run;
      run += c;
    }
  }
  __syncthreads();

  // placement: single traversal, exact slots, plain ds_write
  for (int it = 0; it < 8; ++it) {
    const int g = it * 64 + hw * 4 + sub;
    const unsigned u = sse[g];
    const int st = (int)(u & 0xFFFF);
    const int n  = (int)(u >> 16) - st;
    const int2* slice = rec + (size_t)g * EPG + st;
    for (int j = j0; j < n; j += 8) {
      int2 r = slice[j];
      const int tl  = (r.x >> 14) & 31;
      const int rk  = (r.x >> 19) & 31;
      const int idx = (int)lpos[tl * LPW + g] + rk;
      if (idx < CAP_SRT) srt[idx] = r;
    }
  }
  __syncthreads();

  // gather: half-wave hw owns targets hw (acc0), hw+16 (acc1); lane = batch
  float acc0 = 0.f, acc1 = 0.f;
  {
    int e        = min(ofs[hw], CAP_SRT);
    const int e1 = min(ofs[hw + 1], CAP_SRT);
    for (; e + 4 <= e1; e += 4) {
      int2 q0 = srt[e], q1 = srt[e + 1], q2 = srt[e + 2], q3 = srt[e + 3];
      float f0 = spikesT[(size_t)(q0.x & 0x3FFF) * 32 + b];
      float f1 = spikesT[(size_t)(q1.x & 0x3FFF) * 32 + b];
      float f2 = spikesT[(size_t)(q2.x & 0x3FFF) * 32 + b];
      float f3 = spikesT[(size_t)(q3.x & 0x3FFF) * 32 + b];
      acc0 = fmaf(__int_as_float(q0.y), f0, acc0);
      acc0 = fmaf(__int_as_float(q1.y), f1, acc0);
      acc0 = fmaf(__int_as_float(q2.y), f2, acc0);
      acc0 = fmaf(__int_as_float(q3.y), f3, acc0);
    }
    for (; e < e1; ++e) {
      int2 q = srt[e];
      acc0 = fmaf(__int_as_float(q.y), spikesT[(size_t)(q.x & 0x3FFF) * 32 + b], acc0);
    }
  }
  {
    int e        = min(ofs[hw + 16], CAP_SRT);
    const int e1 = min(ofs[hw + 17], CAP_SRT);
    for (; e + 4 <= e1; e += 4) {
      int2 q0 = srt[e], q1 = srt[e + 1], q2 = srt[e + 2], q3 = srt[e + 3];
      float f0 = spikesT[(size_t)(q0.x & 0x3FFF) * 32 + b];
      float f1 = spikesT[(size_t)(q1.x & 0x3FFF) * 32 + b];
      float f2 = spikesT[(size_t)(q2.x & 0x3FFF) * 32 + b];
      float f3 = spikesT[(size_t)(q3.x & 0x3FFF) * 32 + b];
      acc1 = fmaf(__int_as_float(q0.y), f0, acc1);
      acc1 = fmaf(__int_as_float(q1.y), f1, acc1);
      acc1 = fmaf(__int_as_float(q2.y), f2, acc1);
      acc1 = fmaf(__int_as_float(q3.y), f3, acc1);
    }
    for (; e < e1; ++e) {
      int2 q = srt[e];
      acc1 = fmaf(__int_as_float(q.y), spikesT[(size_t)(q.x & 0x3FFF) * 32 + b], acc1);
    }
  }

  // transpose 32x32 tile and write out coalesced
  otile[hw][b]      = acc0;
  otile[hw + 16][b] = acc1;
  __syncthreads();
  const int bb = tid >> 4;
  const int cc = (tid & 15) * 2;
  float2 o2 = make_float2(otile[cc][bb], otile[cc + 1][bb]);
  *reinterpret_cast<float2*>(&out[(size_t)bb * T_ + k * 32 + cc]) = o2;
}

// ---------------------------------------------------------------------------
__global__ void zero_floats(float* __restrict__ p, int n) {
  int i = blockIdx.x * blockDim.x + threadIdx.x;
  if (i < n) p[i] = 0.0f;
}

// Emergency fallback (tiny ws): direct global atomics, weights inline.
__global__ void naive_kernel(const float* __restrict__ spikes,
                             const float* __restrict__ att,
                             const int*   __restrict__ tgt,
                             const int*   __restrict__ del,
                             float*       __restrict__ out) {
  int i = blockIdx.x * blockDim.x + threadIdx.x;
  if (i >= NEDGES) return;
  int   s = i >> 6;
  int   t = tgt[i];
  float w = edge_weight(att[i], del[i]);
  for (int b = 0; b < B_; ++b)
    unsafeAtomicAdd(&out[(size_t)b * T_ + t], w * spikes[(size_t)b * S_ + s]);
}

// ---------------------------------------------------------------------------
extern "C" void kernel_launch(void* const* d_in, const int* in_sizes, int n_in,
                              void* d_out, int out_size, void* d_ws, size_t ws_size,
                              hipStream_t stream) {
  const float* spikes = (const float*)d_in[0];
  const float* att    = (const float*)d_in[1];
  const int*   tgt    = (const int*)d_in[2];
  const int*   del    = (const int*)d_in[3];
  float*       out    = (float*)d_out;

  const size_t spikesT_bytes = (size_t)S_ * B_ * sizeof(float);           // 2 MB
  const size_t rec_bytes     = (size_t)NEDGES * sizeof(int2);             // 8 MB
  const size_t ofse_bytes    = (size_t)GP_ * NBKT * sizeof(unsigned);     // 1 MB
  const size_t cntm_bytes    = (size_t)GP_ * NBKT * 8 * sizeof(unsigned); // 8 MB
  const size_t need = spikesT_bytes + rec_bytes + ofse_bytes + cntm_bytes + 64;

  if (ws_size < need) {
    zero_floats<<<(B_ * T_ + 255) / 256, 256, 0, stream>>>(out, B_ * T_);
    naive_kernel<<<(NEDGES + 255) / 256, 256, 0, stream>>>(spikes, att, tgt, del, out);
    return;
  }

  char* p = (char*)d_ws;
  float*    spikesT = (float*)p;    p += spikesT_bytes;
  int2*     rec     = (int2*)p;     p += rec_bytes;
  unsigned* cntm    = (unsigned*)p; p += cntm_bytes;
  unsigned* ofse    = (unsigned*)p;

  produce<<<GP_, 512, 0, stream>>>(spikes, att, tgt, del, spikesT, rec, ofse, cntm);
  consume<<<NBKT, 512, 0, stream>>>(rec, ofse, cntm, spikesT, out);
}